// Round 20
// baseline (220.847 us; speedup 1.0000x reference)
//
#include <hip/hip_runtime.h>

#define NF 512
#define NH 3
#define NC 7
#define RB 128         // rows per dst bucket (power of two)
#define RBS 7          // log2(RB)
#define G1 256         // edge slice blocks for hist/sort
#define NBMAX 1024     // max buckets (N <= 131072)
#define LDSCAP 8192    // records per LDS chunk in fused agg (mean bucket ~4096)

// ---------- common ----------

__device__ __forceinline__ int load_idx(const void* base, long long i, int is32) {
    return is32 ? ((const int*)base)[i] : (int)((const long long*)base)[i];
}

__device__ __forceinline__ int detect_is32(const int* __restrict__ ei, int E, int* anynz) {
    if (threadIdx.x == 0) *anynz = 0;
    __syncthreads();
    int lim = E < 2048 ? E : 2048;
    int nz = 0;
    for (int i = threadIdx.x; i < lim; i += blockDim.x) nz |= ei[2 * i + 1];
    if (nz) atomicOr(anynz, 1);
    __syncthreads();
    return *anynz;
}

// GEMM role: grid-stride waves over rows [row0,row1), W slice in registers.
// Writes y4[row].xyz = x[row]@W (UNSCALED). Never touches .w (deg owns it).
__device__ __forceinline__ void gemm_rows(const float* __restrict__ x, const float* __restrict__ W,
                                          float* __restrict__ y4f, int row0, int row1,
                                          int wid, int nwaves) {
    int lane = threadIdx.x & 63;
    float4 w4[6];
    const float4* wp = (const float4*)W;
#pragma unroll
    for (int j = 0; j < 6; ++j) w4[j] = wp[lane * 6 + j];
    const float* wf = (const float*)w4;
    for (int row = row0 + wid; row < row1; row += nwaves) {
        const float4* xp = (const float4*)(x + (size_t)row * NF) + lane * 2;
        float4 a = xp[0], b = xp[1];
        float xv[8] = {a.x, a.y, a.z, a.w, b.x, b.y, b.z, b.w};
        float s0 = 0.f, s1 = 0.f, s2 = 0.f;
#pragma unroll
        for (int j = 0; j < 8; ++j) {
            s0 += xv[j] * wf[j * 3 + 0];
            s1 += xv[j] * wf[j * 3 + 1];
            s2 += xv[j] * wf[j * 3 + 2];
        }
#pragma unroll
        for (int off = 32; off; off >>= 1) {
            s0 += __shfl_down(s0, off);
            s1 += __shfl_down(s1, off);
            s2 += __shfl_down(s2, off);
        }
        if (lane == 0) {
            *(float2*)(y4f + 4 * (size_t)row) = make_float2(s0, s1);
            y4f[4 * (size_t)row + 2] = s2;
        }
    }
}

// ---------- fast path: hist -> sort(self-scanning) -> deg(+rs) -> fused agg ----------

// K1: blocks [0,G1) histogram their edge slice (raw counts into hist);
//     blocks [G1,..) run gemm rows [0,row1)
__global__ __launch_bounds__(256) void k_histgemm(const void* __restrict__ ei, int* __restrict__ hist,
                                                  int E, int NBv,
                                                  const float* __restrict__ x, const float* __restrict__ W,
                                                  float* __restrict__ y4f, int row1) {
    __shared__ int cnt[NBMAX];
    __shared__ int anynz;
    if (blockIdx.x < G1) {
        int is32 = detect_is32((const int*)ei, E, &anynz);
        for (int i = threadIdx.x; i < NBv; i += 256) cnt[i] = 0;
        __syncthreads();
        int EB = (E + G1 - 1) / G1;
        int e0 = blockIdx.x * EB;
        int e1 = min(E, e0 + EB);
        for (int i = e0 + threadIdx.x; i < e1; i += 256) {
            int d = load_idx(ei, (long long)E + i, is32);
            atomicAdd(&cnt[d >> RBS], 1);
        }
        __syncthreads();
        for (int b = threadIdx.x; b < NBv; b += 256)
            hist[b * G1 + blockIdx.x] = cnt[b];
    } else {
        int gb = gridDim.x - G1;
        gemm_rows(x, W, y4f, 0, row1, (blockIdx.x - G1) * 4 + (threadIdx.x >> 6), gb * 4);
    }
}

// K3: blocks [0,G1): SELF-SCANNING counting-sort. Each block derives, from the
//     raw hist table (L2-hot 800KB): pre[b] = sum_{g<blk} hist[b][g] (its own
//     write offset within bucket) and tot[b] (bucket totals) via coalesced
//     per-wave column sums; then in-block exclusive scan of ceil4(tot) -> bst;
//     cur[b] = bst[b]+pre[b]; scatter. Block 0 persists bstart+bcount.
//     This replaces the former separate scan kernel (K2).  Rest: gemm [row1,row2).
__global__ __launch_bounds__(256) void k_sortgemm(const void* __restrict__ ei,
                                                  const int* __restrict__ hist,
                                                  int* __restrict__ bstart, int* __restrict__ bcount,
                                                  unsigned* __restrict__ recs, int E, int NBv,
                                                  const float* __restrict__ x, const float* __restrict__ W,
                                                  float* __restrict__ y4f, int row1, int row2) {
    __shared__ int tot[NBMAX];
    __shared__ int pre[NBMAX];
    __shared__ int bst[NBMAX];
    __shared__ int cur[NBMAX];
    __shared__ int wsum[4];
    __shared__ int anynz;
    if (blockIdx.x < G1) {
        int is32 = detect_is32((const int*)ei, E, &anynz);
        int t = threadIdx.x, lane = t & 63, w = t >> 6;
        int blk = blockIdx.x;
        // per-wave coalesced column sums: bucket b handled by wave (b&3)
        for (int b = w; b < NBv; b += 4) {
            int sp = 0, st = 0;
            const int* hb = &hist[b * G1];
#pragma unroll
            for (int g0 = 0; g0 < G1; g0 += 64) {
                int v = hb[g0 + lane];
                st += v;
                if (g0 + lane < blk) sp += v;
            }
#pragma unroll
            for (int o = 32; o; o >>= 1) {
                st += __shfl_down(st, o);
                sp += __shfl_down(sp, o);
            }
            if (lane == 0) { tot[b] = st; pre[b] = sp; }
        }
        __syncthreads();
        // exclusive scan of ceil4(tot) -> bst (4 buckets/thread, 1024 slots)
        int b4 = t * 4;
        int v[4];
        int s = 0;
#pragma unroll
        for (int j = 0; j < 4; ++j) {
            v[j] = (b4 + j < NBv) ? ((tot[b4 + j] + 3) & ~3) : 0;   // ceil4 padding
            s += v[j];
        }
        int incl = s;
#pragma unroll
        for (int off = 1; off < 64; off <<= 1) {
            int tt = __shfl_up(incl, off);
            if (lane >= off) incl += tt;
        }
        if (lane == 63) wsum[w] = incl;
        __syncthreads();
        int p = 0;
        for (int j = 0; j < w; ++j) p += wsum[j];
        int run = p + incl - s;
#pragma unroll
        for (int j = 0; j < 4; ++j) {
            if (b4 + j < NBMAX) bst[b4 + j] = run;
            run += v[j];
        }
        __syncthreads();
        for (int b = t; b < NBv; b += 256)
            cur[b] = bst[b] + pre[b];
        if (blk == 0)
            for (int b = t; b < NBv; b += 256) { bstart[b] = bst[b]; bcount[b] = tot[b]; }
        __syncthreads();
        int EB = (E + G1 - 1) / G1;
        int e0 = blk * EB;
        int e1 = min(E, e0 + EB);
        for (int i = e0 + t; i < e1; i += 256) {
            int sv = load_idx(ei, i, is32);
            int d = load_idx(ei, (long long)E + i, is32);
            int b = d >> RBS;
            int pos = atomicAdd(&cur[b], 1);      // LDS cursor only
            recs[pos] = ((unsigned)(d & (RB - 1)) << 17) | (unsigned)sv;
        }
    } else {
        int gb = gridDim.x - G1;
        gemm_rows(x, W, y4f, row1, row2, (blockIdx.x - G1) * 4 + (threadIdx.x >> 6), gb * 4);
    }
}

// K4: blocks [0,NBv): per-bucket row histogram -> y4.w = rsqrt(deg+1) AND
//     row-offset table rs[b][r] (absolute, 129 ints). rest gemm rows [row2,N).
__global__ __launch_bounds__(256) void k_deggemm(const unsigned* __restrict__ recs,
                                                 const int* __restrict__ bstart, const int* __restrict__ bcount,
                                                 float* __restrict__ y4f, int* __restrict__ rs,
                                                 int n, int NBv,
                                                 const float* __restrict__ x, const float* __restrict__ W,
                                                 int row2) {
    __shared__ int cnt[RB];
    if (blockIdx.x < (unsigned)NBv) {
        int t = threadIdx.x;
        for (int i = t; i < RB; i += 256) cnt[i] = 0;
        __syncthreads();
        int b = blockIdx.x;
        int s0 = bstart[b], s1 = s0 + bcount[b];
        for (int i = s0 + t; i < s1; i += 256)
            atomicAdd(&cnt[recs[i] >> 17], 1);
        __syncthreads();
        int rbase = b << RBS;
        for (int r = t; r < RB; r += 256) {
            int row = rbase + r;
            if (row < n) y4f[4 * (size_t)row + 3] = rsqrtf((float)(cnt[r] + 1));
        }
        // wave0: exclusive scan of 128 row counts -> absolute offsets in rs
        if (t < 64) {
            int cA = cnt[2 * t], cB = cnt[2 * t + 1];
            int s = cA + cB;
            int incl = s;
#pragma unroll
            for (int off = 1; off < 64; off <<= 1) {
                int tt = __shfl_up(incl, off);
                if (t >= off) incl += tt;
            }
            int ex = s0 + incl - s;
            int* rsb = rs + (size_t)b * (RB + 1);
            rsb[2 * t] = ex;
            rsb[2 * t + 1] = ex + cA;
            if (t == 63) rsb[RB] = ex + s;    // == s0 + cntb
        }
    } else {
        int gb = gridDim.x - NBv;
        gemm_rows(x, W, y4f, row2, n, (blockIdx.x - NBv) * 4 + (threadIdx.x >> 6), gb * 4);
    }
}

// K5: one block per bucket. Single-chunk fast path (bucket <= LDSCAP, ~always):
// offsets from rs (no histogram, no scan) -> rescatter into LDS lrec ->
// row-order register agg (8-lane group per row). Chunked fallback retained.
__global__ __launch_bounds__(256) void k_aggrow(const unsigned* __restrict__ recs,
                                                const int* __restrict__ bstart, const int* __restrict__ bcount,
                                                const int* __restrict__ rs,
                                                const float4* __restrict__ y4, const float* __restrict__ bg,
                                                const float* __restrict__ Wo, const float* __restrict__ bo,
                                                float* __restrict__ outH, float* __restrict__ outZ, int n) {
    __shared__ int cnt[RB];
    __shared__ int cur[RB];
    __shared__ int rsl[RB + 1];
    __shared__ int lrec[LDSCAP];
    int b = blockIdx.x, t = threadIdx.x;
    int grp = t >> 3, sub = t & 7;         // 32 groups x 8 lanes
    int s0 = bstart[b], cntb = bcount[b];
    float acc[4][3] = {{0.f, 0.f, 0.f}, {0.f, 0.f, 0.f}, {0.f, 0.f, 0.f}, {0.f, 0.f, 0.f}};
    if (cntb <= LDSCAP) {
        const int* rsb = rs + (size_t)b * (RB + 1);
        for (int i = t; i <= RB; i += 256) {
            int v = rsb[i] - s0;
            rsl[i] = v;
            if (i < RB) cur[i] = v;
        }
        __syncthreads();
        for (int i = s0 + t; i < s0 + cntb; i += 256) {
            unsigned rec = recs[i];
            int pos = atomicAdd(&cur[rec >> 17], 1);
            lrec[pos] = (int)(rec & 0x1FFFF);
        }
        __syncthreads();
#pragma unroll
        for (int k = 0; k < 4; ++k) {
            int rr = grp + k * 32;
            int e0 = rsl[rr], e1 = rsl[rr + 1];
            for (int i = e0 + sub; i < e1; i += 8) {
                float4 v = y4[lrec[i]];
                acc[k][0] += v.w * v.x;
                acc[k][1] += v.w * v.y;
                acc[k][2] += v.w * v.z;
            }
        }
    } else {
        for (int c0 = s0; c0 < s0 + cntb; c0 += LDSCAP) {
            int c1 = min(s0 + cntb, c0 + LDSCAP);
            for (int i = t; i < RB; i += 256) cnt[i] = 0;
            __syncthreads();
            for (int i = c0 + t; i < c1; i += 256)
                atomicAdd(&cnt[recs[i] >> 17], 1);
            __syncthreads();
            if (t < 64) {
                int cA = cnt[2 * t], cB = cnt[2 * t + 1];
                int s = cA + cB;
                int incl = s;
#pragma unroll
                for (int off = 1; off < 64; off <<= 1) {
                    int tt = __shfl_up(incl, off);
                    if (t >= off) incl += tt;
                }
                int ex = incl - s;
                rsl[2 * t] = ex;
                rsl[2 * t + 1] = ex + cA;
                cur[2 * t] = ex;
                cur[2 * t + 1] = ex + cA;
                if (t == 63) rsl[RB] = ex + s;
            }
            __syncthreads();
            for (int i = c0 + t; i < c1; i += 256) {
                unsigned rec = recs[i];
                int pos = atomicAdd(&cur[rec >> 17], 1);
                lrec[pos] = (int)(rec & 0x1FFFF);
            }
            __syncthreads();
#pragma unroll
            for (int k = 0; k < 4; ++k) {
                int rr = grp + k * 32;
                int e0 = rsl[rr], e1 = rsl[rr + 1];
                for (int i = e0 + sub; i < e1; i += 8) {
                    float4 v = y4[lrec[i]];
                    acc[k][0] += v.w * v.x;
                    acc[k][1] += v.w * v.y;
                    acc[k][2] += v.w * v.z;
                }
            }
            __syncthreads();
        }
    }
    float b0 = bg[0], b1 = bg[1], b2 = bg[2];
    int rbase = b << RBS;
#pragma unroll
    for (int k = 0; k < 4; ++k) {
        float a0 = acc[k][0], a1 = acc[k][1], a2 = acc[k][2];
#pragma unroll
        for (int o = 4; o; o >>= 1) {
            a0 += __shfl_xor(a0, o);
            a1 += __shfl_xor(a1, o);
            a2 += __shfl_xor(a2, o);
        }
        if (sub == 0) {
            int row = rbase + grp + k * 32;
            if (row < n) {
                float4 yv = y4[row];
                float di = yv.w;
                float h0 = fmaxf(di * (a0 + di * yv.x) + b0, 0.f);
                float h1 = fmaxf(di * (a1 + di * yv.y) + b1, 0.f);
                float h2 = fmaxf(di * (a2 + di * yv.z) + b2, 0.f);
                outH[row * 3 + 0] = h0; outH[row * 3 + 1] = h1; outH[row * 3 + 2] = h2;
#pragma unroll
                for (int c = 0; c < NC; ++c)
                    outZ[row * NC + c] = h0 * Wo[c] + h1 * Wo[NC + c] + h2 * Wo[2 * NC + c] + bo[c];
            }
        }
    }
}

// ---------- atomic fallback (round-1 structure) ----------

__global__ void k_detect_fb(const int* ei, int* flag, int E) {
    __shared__ int anynz;
    if (threadIdx.x == 0) anynz = 0;
    __syncthreads();
    int lim = E < 2048 ? E : 2048;
    int nz = 0;
    for (int i = threadIdx.x; i < lim; i += blockDim.x) nz |= ei[2 * i + 1];
    if (nz) atomicOr(&anynz, 1);
    __syncthreads();
    if (threadIdx.x == 0) *flag = anynz;
}
__global__ void k_init_fb(float* deg, int n) {
    int i = blockIdx.x * blockDim.x + threadIdx.x;
    if (i < n) deg[i] = 1.0f;
}
__global__ void k_degc_fb(const void* ei, const int* flag, float* deg, int E, int n) {
    int i = blockIdx.x * blockDim.x + threadIdx.x;
    if (i >= E) return;
    int d = load_idx(ei, (long long)E + i, *flag);
    if ((unsigned)d < (unsigned)n) atomicAdd(&deg[d], 1.0f);
}
__global__ __launch_bounds__(256) void k_gemm_fb(const float* x, const float* W, float* degdis,
                                                 float* xw, float* agg, int n) {
    __shared__ float wl[NF * NH];
    for (int j = threadIdx.x; j < NF * NH; j += 256) wl[j] = W[j];
    __syncthreads();
    int row = blockIdx.x * 4 + (threadIdx.x >> 6);
    if (row >= n) return;
    int lane = threadIdx.x & 63;
    const float4* xp = (const float4*)(x + (size_t)row * NF + lane * 8);
    float4 a = xp[0], b = xp[1];
    float xv[8] = {a.x, a.y, a.z, a.w, b.x, b.y, b.z, b.w};
    float s0 = 0.f, s1 = 0.f, s2 = 0.f;
    int f0 = lane * 8;
#pragma unroll
    for (int j = 0; j < 8; ++j) {
        float v = xv[j];
        const float* wp = &wl[(f0 + j) * NH];
        s0 += v * wp[0]; s1 += v * wp[1]; s2 += v * wp[2];
    }
#pragma unroll
    for (int off = 32; off; off >>= 1) {
        s0 += __shfl_down(s0, off); s1 += __shfl_down(s1, off); s2 += __shfl_down(s2, off);
    }
    if (lane == 0) {
        float d = degdis[row];
        float di = d > 0.f ? rsqrtf(d) : 0.f;
        degdis[row] = di;
        xw[row * 3 + 0] = s0; xw[row * 3 + 1] = s1; xw[row * 3 + 2] = s2;
        float n2 = di * di;
        agg[row * 3 + 0] = s0 * n2; agg[row * 3 + 1] = s1 * n2; agg[row * 3 + 2] = s2 * n2;
    }
}
__global__ void k_scat_fb(const void* ei, const int* flag, const float* dis, const float* xw,
                          float* agg, int E, int n) {
    int i = blockIdx.x * blockDim.x + threadIdx.x;
    if (i >= E) return;
    int is32 = *flag;
    int s = load_idx(ei, i, is32);
    int d = load_idx(ei, (long long)E + i, is32);
    if ((unsigned)s >= (unsigned)n || (unsigned)d >= (unsigned)n) return;
    float w = dis[s] * dis[d];
    atomicAdd(&agg[d * 3 + 0], xw[s * 3 + 0] * w);
    atomicAdd(&agg[d * 3 + 1], xw[s * 3 + 1] * w);
    atomicAdd(&agg[d * 3 + 2], xw[s * 3 + 2] * w);
}
__global__ void k_final_fb(const float* agg, const float* bg, const float* Wo, const float* bo,
                           float* outH, float* outZ, int n) {
    int i = blockIdx.x * blockDim.x + threadIdx.x;
    if (i >= n) return;
    float h0 = fmaxf(agg[i * 3 + 0] + bg[0], 0.f);
    float h1 = fmaxf(agg[i * 3 + 1] + bg[1], 0.f);
    float h2 = fmaxf(agg[i * 3 + 2] + bg[2], 0.f);
    outH[i * 3 + 0] = h0; outH[i * 3 + 1] = h1; outH[i * 3 + 2] = h2;
#pragma unroll
    for (int c = 0; c < NC; ++c)
        outZ[i * NC + c] = h0 * Wo[c] + h1 * Wo[NC + c] + h2 * Wo[2 * NC + c] + bo[c];
}

// ---------- launch ----------

extern "C" void kernel_launch(void* const* d_in, const int* in_sizes, int n_in,
                              void* d_out, int out_size, void* d_ws, size_t ws_size,
                              hipStream_t stream) {
    const float* x  = (const float*)d_in[0];
    const void*  ei = d_in[1];
    const float* Wg = (const float*)d_in[2];
    const float* bg = (const float*)d_in[3];
    const float* Wo = (const float*)d_in[4];
    const float* bo = (const float*)d_in[5];

    const int N = in_sizes[0] / NF;
    const int E = in_sizes[1] / 2;
    const int NBv = (N + RB - 1) >> RBS;

    float* outH = (float*)d_out;
    float* outZ = outH + (size_t)3 * N;

    int*   wsI = (int*)d_ws;
    float* wsF = (float*)d_ws;

    size_t off = 64;
    int* hist   = wsI + off; off += (size_t)NBMAX * G1;
    int* bstart = wsI + off; off += NBMAX;
    int* bcount = wsI + off; off += NBMAX;
    int* rs     = wsI + off; off += (size_t)NBMAX * (RB + 1);
    off = (off + 3) & ~(size_t)3;
    float* y4   = wsF + off; off += (size_t)4 * N;
    unsigned* recs = (unsigned*)(wsI + off); off += (size_t)E + 4 * NBMAX;  // ceil4 pads

    bool fast = (off * 4 <= ws_size) && (N <= 131072) && (NBv <= NBMAX);

    if (fast) {
        // gemm row fractions co-scheduled with each CSR phase
        // (K2 eliminated; its share redistributed: 32 / 46 / 22)
        int r1 = (int)((long long)N * 32 / 100);
        int r2 = (int)((long long)N * 78 / 100);
        k_histgemm<<<G1 + 512, dim3(256), 0, stream>>>(ei, hist, E, NBv, x, Wg, y4, r1);
        k_sortgemm<<<G1 + 896, dim3(256), 0, stream>>>(ei, hist, bstart, bcount, recs, E, NBv,
                                                       x, Wg, y4, r1, r2);
        k_deggemm<<<NBv + 512, dim3(256), 0, stream>>>(recs, bstart, bcount, y4, rs,
                                                       N, NBv, x, Wg, r2);
        k_aggrow<<<NBv, dim3(256), 0, stream>>>(recs, bstart, bcount, rs, (const float4*)y4,
                                                bg, Wo, bo, outH, outZ, N);
    } else {
        int* flag  = wsI;
        float* deg = wsF + 64;
        float* xw  = deg + N;
        float* agg = xw + (size_t)3 * N;
        int gN = (N + 255) / 256, gE = (E + 255) / 256;
        dim3 blk(256);
        k_detect_fb<<<1, blk, 0, stream>>>((const int*)ei, flag, E);
        k_init_fb<<<gN, blk, 0, stream>>>(deg, N);
        k_degc_fb<<<gE, blk, 0, stream>>>(ei, flag, deg, E, N);
        k_gemm_fb<<<(N + 3) / 4, blk, 0, stream>>>(x, Wg, deg, xw, agg, N);
        k_scat_fb<<<gE, blk, 0, stream>>>(ei, flag, deg, xw, agg, E, N);
        k_final_fb<<<gN, blk, 0, stream>>>(agg, bg, Wo, bo, outH, outZ, N);
    }
}

// Round 21
// 107.371 us; speedup vs baseline: 2.0569x; 2.0569x over previous
//
#include <hip/hip_runtime.h>

#define NF 512
#define NH 3
#define NC 7
#define RB 128         // rows per dst bucket (power of two)
#define RBS 7          // log2(RB)
#define G1 256         // edge slice blocks for hist/sort
#define NBMAX 1024     // max buckets (N <= 131072)
#define LDSCAP 8192    // records per LDS chunk in fused agg (mean bucket ~4096)

// ---------- common ----------

__device__ __forceinline__ int load_idx(const void* base, long long i, int is32) {
    return is32 ? ((const int*)base)[i] : (int)((const long long*)base)[i];
}

__device__ __forceinline__ int detect_is32(const int* __restrict__ ei, int E, int* anynz) {
    if (threadIdx.x == 0) *anynz = 0;
    __syncthreads();
    int lim = E < 2048 ? E : 2048;
    int nz = 0;
    for (int i = threadIdx.x; i < lim; i += blockDim.x) nz |= ei[2 * i + 1];
    if (nz) atomicOr(anynz, 1);
    __syncthreads();
    return *anynz;
}

// GEMM role: grid-stride waves over rows [row0,row1), W slice in registers.
// Writes y4[row].xyz = x[row]@W (UNSCALED). Never touches .w (deg owns it).
__device__ __forceinline__ void gemm_rows(const float* __restrict__ x, const float* __restrict__ W,
                                          float* __restrict__ y4f, int row0, int row1,
                                          int wid, int nwaves) {
    int lane = threadIdx.x & 63;
    float4 w4[6];
    const float4* wp = (const float4*)W;
#pragma unroll
    for (int j = 0; j < 6; ++j) w4[j] = wp[lane * 6 + j];
    const float* wf = (const float*)w4;
    for (int row = row0 + wid; row < row1; row += nwaves) {
        const float4* xp = (const float4*)(x + (size_t)row * NF) + lane * 2;
        float4 a = xp[0], b = xp[1];
        float xv[8] = {a.x, a.y, a.z, a.w, b.x, b.y, b.z, b.w};
        float s0 = 0.f, s1 = 0.f, s2 = 0.f;
#pragma unroll
        for (int j = 0; j < 8; ++j) {
            s0 += xv[j] * wf[j * 3 + 0];
            s1 += xv[j] * wf[j * 3 + 1];
            s2 += xv[j] * wf[j * 3 + 2];
        }
#pragma unroll
        for (int off = 32; off; off >>= 1) {
            s0 += __shfl_down(s0, off);
            s1 += __shfl_down(s1, off);
            s2 += __shfl_down(s2, off);
        }
        if (lane == 0) {
            *(float2*)(y4f + 4 * (size_t)row) = make_float2(s0, s1);
            y4f[4 * (size_t)row + 2] = s2;
        }
    }
}

// ---------- fast path: hist -> scan -> sort -> deg(+rs) -> fused(LDS rescatter + reg agg) ----------

// K1: blocks [0,G1) histogram their edge slice; blocks [G1,..) run gemm rows [0,row1)
__global__ __launch_bounds__(256) void k_histgemm(const void* __restrict__ ei, int* __restrict__ hist,
                                                  int E, int NBv,
                                                  const float* __restrict__ x, const float* __restrict__ W,
                                                  float* __restrict__ y4f, int row1) {
    __shared__ int cnt[NBMAX];
    __shared__ int anynz;
    if (blockIdx.x < G1) {
        int is32 = detect_is32((const int*)ei, E, &anynz);
        for (int i = threadIdx.x; i < NBv; i += 256) cnt[i] = 0;
        __syncthreads();
        int EB = (E + G1 - 1) / G1;
        int e0 = blockIdx.x * EB;
        int e1 = min(E, e0 + EB);
        for (int i = e0 + threadIdx.x; i < e1; i += 256) {
            int d = load_idx(ei, (long long)E + i, is32);
            atomicAdd(&cnt[d >> RBS], 1);
        }
        __syncthreads();
        for (int b = threadIdx.x; b < NBv; b += 256)
            hist[b * G1 + blockIdx.x] = cnt[b];
    } else {
        int gb = gridDim.x - G1;
        gemm_rows(x, W, y4f, 0, row1, (blockIdx.x - G1) * 4 + (threadIdx.x >> 6), gb * 4);
    }
}

// K2: blocks [0,NBv) per-bucket exclusive scan of G1 counts; rest gemm [row1,row2)
__global__ __launch_bounds__(256) void k_scangemm(int* __restrict__ hist, int* __restrict__ bcount,
                                                  int NBv,
                                                  const float* __restrict__ x, const float* __restrict__ W,
                                                  float* __restrict__ y4f, int row1, int row2) {
    __shared__ int wsum[4];
    if (blockIdx.x < (unsigned)NBv) {
        int b = blockIdx.x;
        int t = threadIdx.x, lane = t & 63, w = t >> 6;
        int v = hist[b * G1 + t];
        int incl = v;
#pragma unroll
        for (int off = 1; off < 64; off <<= 1) {
            int tt = __shfl_up(incl, off);
            if (lane >= off) incl += tt;
        }
        if (lane == 63) wsum[w] = incl;
        __syncthreads();
        int p = 0;
        for (int j = 0; j < w; ++j) p += wsum[j];
        hist[b * G1 + t] = p + incl - v;          // bucket-local exclusive
        if (t == 255) bcount[b] = p + incl;       // bucket total (raw)
    } else {
        int gb = gridDim.x - NBv;
        gemm_rows(x, W, y4f, row1, row2, (blockIdx.x - NBv) * 4 + (threadIdx.x >> 6), gb * 4);
    }
}

// K3: blocks [0,G1) counting-sort scatter (redundant bstart scan from bcount,
//     bucket bases padded to 4-record alignment); rest gemm rows [row2,row3).
//     Block 0 persists bstart.
__global__ __launch_bounds__(256) void k_sortgemm(const void* __restrict__ ei,
                                                  const int* __restrict__ hist,
                                                  const int* __restrict__ bcount,
                                                  int* __restrict__ bstart,
                                                  unsigned* __restrict__ recs, int E, int NBv,
                                                  const float* __restrict__ x, const float* __restrict__ W,
                                                  float* __restrict__ y4f, int row2, int row3) {
    __shared__ int bst[NBMAX];
    __shared__ int cur[NBMAX];
    __shared__ int wsum[4];
    __shared__ int anynz;
    if (blockIdx.x < G1) {
        int is32 = detect_is32((const int*)ei, E, &anynz);
        int t = threadIdx.x, lane = t & 63, w = t >> 6;
        int b4 = t * 4;
        int v[4];
        int s = 0;
#pragma unroll
        for (int j = 0; j < 4; ++j) {
            v[j] = (b4 + j < NBv) ? ((bcount[b4 + j] + 3) & ~3) : 0;   // ceil4 padding
            s += v[j];
        }
        int incl = s;
#pragma unroll
        for (int off = 1; off < 64; off <<= 1) {
            int tt = __shfl_up(incl, off);
            if (lane >= off) incl += tt;
        }
        if (lane == 63) wsum[w] = incl;
        __syncthreads();
        int p = 0;
        for (int j = 0; j < w; ++j) p += wsum[j];
        int run = p + incl - s;
#pragma unroll
        for (int j = 0; j < 4; ++j) {
            if (b4 + j < NBMAX) bst[b4 + j] = run;
            run += v[j];
        }
        __syncthreads();
        for (int b = t; b < NBv; b += 256)
            cur[b] = bst[b] + hist[b * G1 + blockIdx.x];
        if (blockIdx.x == 0)
            for (int b = t; b < NBv; b += 256) bstart[b] = bst[b];
        __syncthreads();
        int EB = (E + G1 - 1) / G1;
        int e0 = blockIdx.x * EB;
        int e1 = min(E, e0 + EB);
        for (int i = e0 + t; i < e1; i += 256) {
            int sv = load_idx(ei, i, is32);
            int d = load_idx(ei, (long long)E + i, is32);
            int b = d >> RBS;
            int pos = atomicAdd(&cur[b], 1);      // LDS cursor only
            recs[pos] = ((unsigned)(d & (RB - 1)) << 17) | (unsigned)sv;
        }
    } else {
        int gb = gridDim.x - G1;
        gemm_rows(x, W, y4f, row2, row3, (blockIdx.x - G1) * 4 + (threadIdx.x >> 6), gb * 4);
    }
}

// K4: blocks [0,NBv): per-bucket row histogram (uint4 record loads, 4/instr) ->
//     y4.w = rsqrt(deg+1) AND row-offset table rs[b][r]. rest gemm rows [row3,N).
__global__ __launch_bounds__(256) void k_deggemm(const unsigned* __restrict__ recs,
                                                 const int* __restrict__ bstart, const int* __restrict__ bcount,
                                                 float* __restrict__ y4f, int* __restrict__ rs,
                                                 int n, int NBv,
                                                 const float* __restrict__ x, const float* __restrict__ W,
                                                 int row3) {
    __shared__ int cnt[RB];
    if (blockIdx.x < (unsigned)NBv) {
        int t = threadIdx.x;
        for (int i = t; i < RB; i += 256) cnt[i] = 0;
        __syncthreads();
        int b = blockIdx.x;
        int s0 = bstart[b], cntb = bcount[b], s1 = s0 + cntb;
        // uint4 main loop (s0 is 16B-aligned via ceil4-padded bst)
        int nv4 = cntb >> 2;
        const uint4* rp4 = (const uint4*)(recs + s0);
        for (int j = t; j < nv4; j += 256) {
            uint4 ra = rp4[j];
            atomicAdd(&cnt[ra.x >> 17], 1);
            atomicAdd(&cnt[ra.y >> 17], 1);
            atomicAdd(&cnt[ra.z >> 17], 1);
            atomicAdd(&cnt[ra.w >> 17], 1);
        }
        for (int i = s0 + (nv4 << 2) + t; i < s1; i += 256)
            atomicAdd(&cnt[recs[i] >> 17], 1);
        __syncthreads();
        int rbase = b << RBS;
        for (int r = t; r < RB; r += 256) {
            int row = rbase + r;
            if (row < n) y4f[4 * (size_t)row + 3] = rsqrtf((float)(cnt[r] + 1));
        }
        // wave0: exclusive scan of 128 row counts -> absolute offsets in rs
        if (t < 64) {
            int cA = cnt[2 * t], cB = cnt[2 * t + 1];
            int s = cA + cB;
            int incl = s;
#pragma unroll
            for (int off = 1; off < 64; off <<= 1) {
                int tt = __shfl_up(incl, off);
                if (t >= off) incl += tt;
            }
            int ex = s0 + incl - s;
            int* rsb = rs + (size_t)b * (RB + 1);
            rsb[2 * t] = ex;
            rsb[2 * t + 1] = ex + cA;
            if (t == 63) rsb[RB] = ex + s;    // == s0 + cntb
        }
    } else {
        int gb = gridDim.x - NBv;
        gemm_rows(x, W, y4f, row3, n, (blockIdx.x - NBv) * 4 + (threadIdx.x >> 6), gb * 4);
    }
}

// K5: one block per bucket. Single-chunk fast path (bucket <= LDSCAP, ~always):
// offsets from rs (no histogram/scan) -> uint4 record loads -> rescatter into
// LDS lrec -> row-order register agg (8-lane group per row). Chunked fallback.
__global__ __launch_bounds__(256) void k_aggrow(const unsigned* __restrict__ recs,
                                                const int* __restrict__ bstart, const int* __restrict__ bcount,
                                                const int* __restrict__ rs,
                                                const float4* __restrict__ y4, const float* __restrict__ bg,
                                                const float* __restrict__ Wo, const float* __restrict__ bo,
                                                float* __restrict__ outH, float* __restrict__ outZ, int n) {
    __shared__ int cnt[RB];
    __shared__ int cur[RB];
    __shared__ int rsl[RB + 1];
    __shared__ int lrec[LDSCAP];
    int b = blockIdx.x, t = threadIdx.x;
    int grp = t >> 3, sub = t & 7;         // 32 groups x 8 lanes
    int s0 = bstart[b], cntb = bcount[b];
    float acc[4][3] = {{0.f, 0.f, 0.f}, {0.f, 0.f, 0.f}, {0.f, 0.f, 0.f}, {0.f, 0.f, 0.f}};
    if (cntb <= LDSCAP) {
        const int* rsb = rs + (size_t)b * (RB + 1);
        for (int i = t; i <= RB; i += 256) {
            int v = rsb[i] - s0;
            rsl[i] = v;
            if (i < RB) cur[i] = v;
        }
        __syncthreads();
        // uint4 rescatter (s0 16B-aligned)
        int nv4 = cntb >> 2;
        const uint4* rp4 = (const uint4*)(recs + s0);
        for (int j = t; j < nv4; j += 256) {
            uint4 ra = rp4[j];
            int p0 = atomicAdd(&cur[ra.x >> 17], 1);
            lrec[p0] = (int)(ra.x & 0x1FFFF);
            int p1 = atomicAdd(&cur[ra.y >> 17], 1);
            lrec[p1] = (int)(ra.y & 0x1FFFF);
            int p2 = atomicAdd(&cur[ra.z >> 17], 1);
            lrec[p2] = (int)(ra.z & 0x1FFFF);
            int p3 = atomicAdd(&cur[ra.w >> 17], 1);
            lrec[p3] = (int)(ra.w & 0x1FFFF);
        }
        for (int i = s0 + (nv4 << 2) + t; i < s0 + cntb; i += 256) {
            unsigned rec = recs[i];
            int pos = atomicAdd(&cur[rec >> 17], 1);
            lrec[pos] = (int)(rec & 0x1FFFF);
        }
        __syncthreads();
#pragma unroll
        for (int k = 0; k < 4; ++k) {
            int rr = grp + k * 32;
            int e0 = rsl[rr], e1 = rsl[rr + 1];
            for (int i = e0 + sub; i < e1; i += 8) {
                float4 v = y4[lrec[i]];
                acc[k][0] += v.w * v.x;
                acc[k][1] += v.w * v.y;
                acc[k][2] += v.w * v.z;
            }
        }
    } else {
        for (int c0 = s0; c0 < s0 + cntb; c0 += LDSCAP) {
            int c1 = min(s0 + cntb, c0 + LDSCAP);
            for (int i = t; i < RB; i += 256) cnt[i] = 0;
            __syncthreads();
            for (int i = c0 + t; i < c1; i += 256)
                atomicAdd(&cnt[recs[i] >> 17], 1);
            __syncthreads();
            if (t < 64) {
                int cA = cnt[2 * t], cB = cnt[2 * t + 1];
                int s = cA + cB;
                int incl = s;
#pragma unroll
                for (int off = 1; off < 64; off <<= 1) {
                    int tt = __shfl_up(incl, off);
                    if (t >= off) incl += tt;
                }
                int ex = incl - s;
                rsl[2 * t] = ex;
                rsl[2 * t + 1] = ex + cA;
                cur[2 * t] = ex;
                cur[2 * t + 1] = ex + cA;
                if (t == 63) rsl[RB] = ex + s;
            }
            __syncthreads();
            for (int i = c0 + t; i < c1; i += 256) {
                unsigned rec = recs[i];
                int pos = atomicAdd(&cur[rec >> 17], 1);
                lrec[pos] = (int)(rec & 0x1FFFF);
            }
            __syncthreads();
#pragma unroll
            for (int k = 0; k < 4; ++k) {
                int rr = grp + k * 32;
                int e0 = rsl[rr], e1 = rsl[rr + 1];
                for (int i = e0 + sub; i < e1; i += 8) {
                    float4 v = y4[lrec[i]];
                    acc[k][0] += v.w * v.x;
                    acc[k][1] += v.w * v.y;
                    acc[k][2] += v.w * v.z;
                }
            }
            __syncthreads();
        }
    }
    float b0 = bg[0], b1 = bg[1], b2 = bg[2];
    int rbase = b << RBS;
#pragma unroll
    for (int k = 0; k < 4; ++k) {
        float a0 = acc[k][0], a1 = acc[k][1], a2 = acc[k][2];
#pragma unroll
        for (int o = 4; o; o >>= 1) {
            a0 += __shfl_xor(a0, o);
            a1 += __shfl_xor(a1, o);
            a2 += __shfl_xor(a2, o);
        }
        if (sub == 0) {
            int row = rbase + grp + k * 32;
            if (row < n) {
                float4 yv = y4[row];
                float di = yv.w;
                float h0 = fmaxf(di * (a0 + di * yv.x) + b0, 0.f);
                float h1 = fmaxf(di * (a1 + di * yv.y) + b1, 0.f);
                float h2 = fmaxf(di * (a2 + di * yv.z) + b2, 0.f);
                outH[row * 3 + 0] = h0; outH[row * 3 + 1] = h1; outH[row * 3 + 2] = h2;
#pragma unroll
                for (int c = 0; c < NC; ++c)
                    outZ[row * NC + c] = h0 * Wo[c] + h1 * Wo[NC + c] + h2 * Wo[2 * NC + c] + bo[c];
            }
        }
    }
}

// ---------- atomic fallback (round-1 structure) ----------

__global__ void k_detect_fb(const int* ei, int* flag, int E) {
    __shared__ int anynz;
    if (threadIdx.x == 0) anynz = 0;
    __syncthreads();
    int lim = E < 2048 ? E : 2048;
    int nz = 0;
    for (int i = threadIdx.x; i < lim; i += blockDim.x) nz |= ei[2 * i + 1];
    if (nz) atomicOr(&anynz, 1);
    __syncthreads();
    if (threadIdx.x == 0) *flag = anynz;
}
__global__ void k_init_fb(float* deg, int n) {
    int i = blockIdx.x * blockDim.x + threadIdx.x;
    if (i < n) deg[i] = 1.0f;
}
__global__ void k_degc_fb(const void* ei, const int* flag, float* deg, int E, int n) {
    int i = blockIdx.x * blockDim.x + threadIdx.x;
    if (i >= E) return;
    int d = load_idx(ei, (long long)E + i, *flag);
    if ((unsigned)d < (unsigned)n) atomicAdd(&deg[d], 1.0f);
}
__global__ __launch_bounds__(256) void k_gemm_fb(const float* x, const float* W, float* degdis,
                                                 float* xw, float* agg, int n) {
    __shared__ float wl[NF * NH];
    for (int j = threadIdx.x; j < NF * NH; j += 256) wl[j] = W[j];
    __syncthreads();
    int row = blockIdx.x * 4 + (threadIdx.x >> 6);
    if (row >= n) return;
    int lane = threadIdx.x & 63;
    const float4* xp = (const float4*)(x + (size_t)row * NF + lane * 8);
    float4 a = xp[0], b = xp[1];
    float xv[8] = {a.x, a.y, a.z, a.w, b.x, b.y, b.z, b.w};
    float s0 = 0.f, s1 = 0.f, s2 = 0.f;
    int f0 = lane * 8;
#pragma unroll
    for (int j = 0; j < 8; ++j) {
        float v = xv[j];
        const float* wp = &wl[(f0 + j) * NH];
        s0 += v * wp[0]; s1 += v * wp[1]; s2 += v * wp[2];
    }
#pragma unroll
    for (int off = 32; off; off >>= 1) {
        s0 += __shfl_down(s0, off); s1 += __shfl_down(s1, off); s2 += __shfl_down(s2, off);
    }
    if (lane == 0) {
        float d = degdis[row];
        float di = d > 0.f ? rsqrtf(d) : 0.f;
        degdis[row] = di;
        xw[row * 3 + 0] = s0; xw[row * 3 + 1] = s1; xw[row * 3 + 2] = s2;
        float n2 = di * di;
        agg[row * 3 + 0] = s0 * n2; agg[row * 3 + 1] = s1 * n2; agg[row * 3 + 2] = s2 * n2;
    }
}
__global__ void k_scat_fb(const void* ei, const int* flag, const float* dis, const float* xw,
                          float* agg, int E, int n) {
    int i = blockIdx.x * blockDim.x + threadIdx.x;
    if (i >= E) return;
    int is32 = *flag;
    int s = load_idx(ei, i, is32);
    int d = load_idx(ei, (long long)E + i, is32);
    if ((unsigned)s >= (unsigned)n || (unsigned)d >= (unsigned)n) return;
    float w = dis[s] * dis[d];
    atomicAdd(&agg[d * 3 + 0], xw[s * 3 + 0] * w);
    atomicAdd(&agg[d * 3 + 1], xw[s * 3 + 1] * w);
    atomicAdd(&agg[d * 3 + 2], xw[s * 3 + 2] * w);
}
__global__ void k_final_fb(const float* agg, const float* bg, const float* Wo, const float* bo,
                           float* outH, float* outZ, int n) {
    int i = blockIdx.x * blockDim.x + threadIdx.x;
    if (i >= n) return;
    float h0 = fmaxf(agg[i * 3 + 0] + bg[0], 0.f);
    float h1 = fmaxf(agg[i * 3 + 1] + bg[1], 0.f);
    float h2 = fmaxf(agg[i * 3 + 2] + bg[2], 0.f);
    outH[i * 3 + 0] = h0; outH[i * 3 + 1] = h1; outH[i * 3 + 2] = h2;
#pragma unroll
    for (int c = 0; c < NC; ++c)
        outZ[i * NC + c] = h0 * Wo[c] + h1 * Wo[NC + c] + h2 * Wo[2 * NC + c] + bo[c];
}

// ---------- launch ----------

extern "C" void kernel_launch(void* const* d_in, const int* in_sizes, int n_in,
                              void* d_out, int out_size, void* d_ws, size_t ws_size,
                              hipStream_t stream) {
    const float* x  = (const float*)d_in[0];
    const void*  ei = d_in[1];
    const float* Wg = (const float*)d_in[2];
    const float* bg = (const float*)d_in[3];
    const float* Wo = (const float*)d_in[4];
    const float* bo = (const float*)d_in[5];

    const int N = in_sizes[0] / NF;
    const int E = in_sizes[1] / 2;
    const int NBv = (N + RB - 1) >> RBS;

    float* outH = (float*)d_out;
    float* outZ = outH + (size_t)3 * N;

    int*   wsI = (int*)d_ws;
    float* wsF = (float*)d_ws;

    size_t off = 64;
    int* hist   = wsI + off; off += (size_t)NBMAX * G1;
    int* bstart = wsI + off; off += NBMAX;
    int* bcount = wsI + off; off += NBMAX;
    int* rs     = wsI + off; off += (size_t)NBMAX * (RB + 1);
    off = (off + 3) & ~(size_t)3;
    float* y4   = wsF + off; off += (size_t)4 * N;
    unsigned* recs = (unsigned*)(wsI + off); off += (size_t)E + 4 * NBMAX;  // ceil4 pads

    bool fast = (off * 4 <= ws_size) && (N <= 131072) && (NBv <= NBMAX);

    if (fast) {
        // gemm row fractions co-scheduled with each CSR phase (R19 values)
        int r1 = (int)((long long)N * 30 / 100);
        int r2 = (int)((long long)N * 36 / 100);
        int r3 = (int)((long long)N * 80 / 100);
        k_histgemm<<<G1 + 512, dim3(256), 0, stream>>>(ei, hist, E, NBv, x, Wg, y4, r1);
        k_scangemm<<<NBv + 128, dim3(256), 0, stream>>>(hist, bcount, NBv, x, Wg, y4, r1, r2);
        k_sortgemm<<<G1 + 896, dim3(256), 0, stream>>>(ei, hist, bcount, bstart, recs, E, NBv,
                                                       x, Wg, y4, r2, r3);
        k_deggemm<<<NBv + 512, dim3(256), 0, stream>>>(recs, bstart, bcount, y4, rs,
                                                       N, NBv, x, Wg, r3);
        k_aggrow<<<NBv, dim3(256), 0, stream>>>(recs, bstart, bcount, rs, (const float4*)y4,
                                                bg, Wo, bo, outH, outZ, N);
    } else {
        int* flag  = wsI;
        float* deg = wsF + 64;
        float* xw  = deg + N;
        float* agg = xw + (size_t)3 * N;
        int gN = (N + 255) / 256, gE = (E + 255) / 256;
        dim3 blk(256);
        k_detect_fb<<<1, blk, 0, stream>>>((const int*)ei, flag, E);
        k_init_fb<<<gN, blk, 0, stream>>>(deg, N);
        k_degc_fb<<<gE, blk, 0, stream>>>(ei, flag, deg, E, N);
        k_gemm_fb<<<(N + 3) / 4, blk, 0, stream>>>(x, Wg, deg, xw, agg, N);
        k_scat_fb<<<gE, blk, 0, stream>>>(ei, flag, deg, xw, agg, E, N);
        k_final_fb<<<gN, blk, 0, stream>>>(agg, bg, Wo, bo, outH, outZ, N);
    }
}

// Round 22
// 100.974 us; speedup vs baseline: 2.1872x; 1.0634x over previous
//
#include <hip/hip_runtime.h>

#define NF 512
#define NH 3
#define NC 7
#define RB 128         // rows per dst bucket (power of two)
#define RBS 7          // log2(RB)
#define G1 256         // edge slice blocks for hist/sort
#define NBMAX 1024     // max buckets (N <= 131072)
#define LDSCAP 8192    // records per LDS chunk in fused agg (mean bucket ~4096)

// ---------- common ----------

__device__ __forceinline__ int load_idx(const void* base, long long i, int is32) {
    return is32 ? ((const int*)base)[i] : (int)((const long long*)base)[i];
}

__device__ __forceinline__ int detect_is32(const int* __restrict__ ei, int E, int* anynz) {
    if (threadIdx.x == 0) *anynz = 0;
    __syncthreads();
    int lim = E < 2048 ? E : 2048;
    int nz = 0;
    for (int i = threadIdx.x; i < lim; i += blockDim.x) nz |= ei[2 * i + 1];
    if (nz) atomicOr(anynz, 1);
    __syncthreads();
    return *anynz;
}

// GEMM role: grid-stride waves over rows [row0,row1), W slice in registers.
// Writes y4[row].xyz = x[row]@W (UNSCALED). Never touches .w (deg owns it).
__device__ __forceinline__ void gemm_rows(const float* __restrict__ x, const float* __restrict__ W,
                                          float* __restrict__ y4f, int row0, int row1,
                                          int wid, int nwaves) {
    int lane = threadIdx.x & 63;
    float4 w4[6];
    const float4* wp = (const float4*)W;
#pragma unroll
    for (int j = 0; j < 6; ++j) w4[j] = wp[lane * 6 + j];
    const float* wf = (const float*)w4;
    for (int row = row0 + wid; row < row1; row += nwaves) {
        const float4* xp = (const float4*)(x + (size_t)row * NF) + lane * 2;
        float4 a = xp[0], b = xp[1];
        float xv[8] = {a.x, a.y, a.z, a.w, b.x, b.y, b.z, b.w};
        float s0 = 0.f, s1 = 0.f, s2 = 0.f;
#pragma unroll
        for (int j = 0; j < 8; ++j) {
            s0 += xv[j] * wf[j * 3 + 0];
            s1 += xv[j] * wf[j * 3 + 1];
            s2 += xv[j] * wf[j * 3 + 2];
        }
#pragma unroll
        for (int off = 32; off; off >>= 1) {
            s0 += __shfl_down(s0, off);
            s1 += __shfl_down(s1, off);
            s2 += __shfl_down(s2, off);
        }
        if (lane == 0) {
            *(float2*)(y4f + 4 * (size_t)row) = make_float2(s0, s1);
            y4f[4 * (size_t)row + 2] = s2;
        }
    }
}

// ---------- fast path: hist -> scan -> sort -> deg(+rs) -> fused(LDS rescatter + reg agg) ----------

// K1: blocks [0,G1) histogram their edge slice (vectorized dst loads);
//     blocks [G1,..) run gemm rows [0,row1)
__global__ __launch_bounds__(256) void k_histgemm(const void* __restrict__ ei, int* __restrict__ hist,
                                                  int E, int NBv,
                                                  const float* __restrict__ x, const float* __restrict__ W,
                                                  float* __restrict__ y4f, int row1) {
    __shared__ int cnt[NBMAX];
    __shared__ int anynz;
    if (blockIdx.x < G1) {
        int is32 = detect_is32((const int*)ei, E, &anynz);
        int t = threadIdx.x;
        for (int i = t; i < NBv; i += 256) cnt[i] = 0;
        __syncthreads();
        int EB = (((E + G1 - 1) / G1) + 3) & ~3;   // x4 so slice bases stay aligned
        int e0 = blockIdx.x * EB;
        int e1 = min(E, e0 + EB);
        if (e0 < e1) {
            if (is32 && ((((long long)E + e0) & 3) == 0)) {
                const int4* dp4 = (const int4*)((const int*)ei + (long long)E + e0);
                int nv4 = (e1 - e0) >> 2;
                for (int j = t; j < nv4; j += 256) {
                    int4 dv = dp4[j];
                    atomicAdd(&cnt[dv.x >> RBS], 1);
                    atomicAdd(&cnt[dv.y >> RBS], 1);
                    atomicAdd(&cnt[dv.z >> RBS], 1);
                    atomicAdd(&cnt[dv.w >> RBS], 1);
                }
                for (int i = e0 + (nv4 << 2) + t; i < e1; i += 256)
                    atomicAdd(&cnt[((const int*)ei)[(long long)E + i] >> RBS], 1);
            } else if (!is32 && ((((long long)E + e0) & 1) == 0)) {
                const longlong2* dp2 = (const longlong2*)((const long long*)ei + (long long)E + e0);
                int nv2 = (e1 - e0) >> 1;
                for (int j = t; j < nv2; j += 256) {
                    longlong2 dv = dp2[j];
                    atomicAdd(&cnt[(int)dv.x >> RBS], 1);
                    atomicAdd(&cnt[(int)dv.y >> RBS], 1);
                }
                for (int i = e0 + (nv2 << 1) + t; i < e1; i += 256)
                    atomicAdd(&cnt[(int)((const long long*)ei)[(long long)E + i] >> RBS], 1);
            } else {
                for (int i = e0 + t; i < e1; i += 256) {
                    int d = load_idx(ei, (long long)E + i, is32);
                    atomicAdd(&cnt[d >> RBS], 1);
                }
            }
        }
        __syncthreads();
        for (int b = t; b < NBv; b += 256)
            hist[b * G1 + blockIdx.x] = cnt[b];
    } else {
        int gb = gridDim.x - G1;
        gemm_rows(x, W, y4f, 0, row1, (blockIdx.x - G1) * 4 + (threadIdx.x >> 6), gb * 4);
    }
}

// K2: blocks [0,NBv) per-bucket exclusive scan of G1 counts; rest gemm [row1,row2)
__global__ __launch_bounds__(256) void k_scangemm(int* __restrict__ hist, int* __restrict__ bcount,
                                                  int NBv,
                                                  const float* __restrict__ x, const float* __restrict__ W,
                                                  float* __restrict__ y4f, int row1, int row2) {
    __shared__ int wsum[4];
    if (blockIdx.x < (unsigned)NBv) {
        int b = blockIdx.x;
        int t = threadIdx.x, lane = t & 63, w = t >> 6;
        int v = hist[b * G1 + t];
        int incl = v;
#pragma unroll
        for (int off = 1; off < 64; off <<= 1) {
            int tt = __shfl_up(incl, off);
            if (lane >= off) incl += tt;
        }
        if (lane == 63) wsum[w] = incl;
        __syncthreads();
        int p = 0;
        for (int j = 0; j < w; ++j) p += wsum[j];
        hist[b * G1 + t] = p + incl - v;          // bucket-local exclusive
        if (t == 255) bcount[b] = p + incl;       // bucket total (raw)
    } else {
        int gb = gridDim.x - NBv;
        gemm_rows(x, W, y4f, row1, row2, (blockIdx.x - NBv) * 4 + (threadIdx.x >> 6), gb * 4);
    }
}

// K3: blocks [0,G1) counting-sort scatter with vectorized edge loads
//     (redundant bstart scan from bcount, bucket bases ceil4-padded);
//     rest gemm rows [row2,row3). Block 0 persists bstart.
__global__ __launch_bounds__(256) void k_sortgemm(const void* __restrict__ ei,
                                                  const int* __restrict__ hist,
                                                  const int* __restrict__ bcount,
                                                  int* __restrict__ bstart,
                                                  unsigned* __restrict__ recs, int E, int NBv,
                                                  const float* __restrict__ x, const float* __restrict__ W,
                                                  float* __restrict__ y4f, int row2, int row3) {
    __shared__ int bst[NBMAX];
    __shared__ int cur[NBMAX];
    __shared__ int wsum[4];
    __shared__ int anynz;
    if (blockIdx.x < G1) {
        int is32 = detect_is32((const int*)ei, E, &anynz);
        int t = threadIdx.x, lane = t & 63, w = t >> 6;
        int b4 = t * 4;
        int v[4];
        int s = 0;
#pragma unroll
        for (int j = 0; j < 4; ++j) {
            v[j] = (b4 + j < NBv) ? ((bcount[b4 + j] + 3) & ~3) : 0;   // ceil4 padding
            s += v[j];
        }
        int incl = s;
#pragma unroll
        for (int off = 1; off < 64; off <<= 1) {
            int tt = __shfl_up(incl, off);
            if (lane >= off) incl += tt;
        }
        if (lane == 63) wsum[w] = incl;
        __syncthreads();
        int p = 0;
        for (int j = 0; j < w; ++j) p += wsum[j];
        int run = p + incl - s;
#pragma unroll
        for (int j = 0; j < 4; ++j) {
            if (b4 + j < NBMAX) bst[b4 + j] = run;
            run += v[j];
        }
        __syncthreads();
        for (int b = t; b < NBv; b += 256)
            cur[b] = bst[b] + hist[b * G1 + blockIdx.x];
        if (blockIdx.x == 0)
            for (int b = t; b < NBv; b += 256) bstart[b] = bst[b];
        __syncthreads();
        int EB = (((E + G1 - 1) / G1) + 3) & ~3;
        int e0 = blockIdx.x * EB;
        int e1 = min(E, e0 + EB);
        if (e0 < e1) {
            if (is32 && ((e0 & 3) == 0) && ((((long long)E + e0) & 3) == 0)) {
                const int4* sp4 = (const int4*)((const int*)ei + e0);
                const int4* dp4 = (const int4*)((const int*)ei + (long long)E + e0);
                int nv4 = (e1 - e0) >> 2;
                for (int j = t; j < nv4; j += 256) {
                    int4 sv = sp4[j];
                    int4 dv = dp4[j];
                    int p0 = atomicAdd(&cur[dv.x >> RBS], 1);
                    recs[p0] = ((unsigned)(dv.x & (RB - 1)) << 17) | (unsigned)sv.x;
                    int p1 = atomicAdd(&cur[dv.y >> RBS], 1);
                    recs[p1] = ((unsigned)(dv.y & (RB - 1)) << 17) | (unsigned)sv.y;
                    int p2 = atomicAdd(&cur[dv.z >> RBS], 1);
                    recs[p2] = ((unsigned)(dv.z & (RB - 1)) << 17) | (unsigned)sv.z;
                    int p3 = atomicAdd(&cur[dv.w >> RBS], 1);
                    recs[p3] = ((unsigned)(dv.w & (RB - 1)) << 17) | (unsigned)sv.w;
                }
                for (int i = e0 + (nv4 << 2) + t; i < e1; i += 256) {
                    int sv = ((const int*)ei)[i];
                    int d = ((const int*)ei)[(long long)E + i];
                    int pos = atomicAdd(&cur[d >> RBS], 1);
                    recs[pos] = ((unsigned)(d & (RB - 1)) << 17) | (unsigned)sv;
                }
            } else if (!is32 && ((e0 & 1) == 0) && ((((long long)E + e0) & 1) == 0)) {
                const longlong2* sp2 = (const longlong2*)((const long long*)ei + e0);
                const longlong2* dp2 = (const longlong2*)((const long long*)ei + (long long)E + e0);
                int nv2 = (e1 - e0) >> 1;
                for (int j = t; j < nv2; j += 256) {
                    longlong2 sv = sp2[j];
                    longlong2 dv = dp2[j];
                    int d0 = (int)dv.x, d1 = (int)dv.y;
                    int p0 = atomicAdd(&cur[d0 >> RBS], 1);
                    recs[p0] = ((unsigned)(d0 & (RB - 1)) << 17) | (unsigned)(int)sv.x;
                    int p1 = atomicAdd(&cur[d1 >> RBS], 1);
                    recs[p1] = ((unsigned)(d1 & (RB - 1)) << 17) | (unsigned)(int)sv.y;
                }
                for (int i = e0 + (nv2 << 1) + t; i < e1; i += 256) {
                    int sv = (int)((const long long*)ei)[i];
                    int d = (int)((const long long*)ei)[(long long)E + i];
                    int pos = atomicAdd(&cur[d >> RBS], 1);
                    recs[pos] = ((unsigned)(d & (RB - 1)) << 17) | (unsigned)sv;
                }
            } else {
                for (int i = e0 + t; i < e1; i += 256) {
                    int sv = load_idx(ei, i, is32);
                    int d = load_idx(ei, (long long)E + i, is32);
                    int b = d >> RBS;
                    int pos = atomicAdd(&cur[b], 1);
                    recs[pos] = ((unsigned)(d & (RB - 1)) << 17) | (unsigned)sv;
                }
            }
        }
    } else {
        int gb = gridDim.x - G1;
        gemm_rows(x, W, y4f, row2, row3, (blockIdx.x - G1) * 4 + (threadIdx.x >> 6), gb * 4);
    }
}

// K4: blocks [0,NBv): per-bucket row histogram (uint4 record loads, 4/instr) ->
//     y4.w = rsqrt(deg+1) AND row-offset table rs[b][r]. rest gemm rows [row3,N).
__global__ __launch_bounds__(256) void k_deggemm(const unsigned* __restrict__ recs,
                                                 const int* __restrict__ bstart, const int* __restrict__ bcount,
                                                 float* __restrict__ y4f, int* __restrict__ rs,
                                                 int n, int NBv,
                                                 const float* __restrict__ x, const float* __restrict__ W,
                                                 int row3) {
    __shared__ int cnt[RB];
    if (blockIdx.x < (unsigned)NBv) {
        int t = threadIdx.x;
        for (int i = t; i < RB; i += 256) cnt[i] = 0;
        __syncthreads();
        int b = blockIdx.x;
        int s0 = bstart[b], cntb = bcount[b], s1 = s0 + cntb;
        int nv4 = cntb >> 2;
        const uint4* rp4 = (const uint4*)(recs + s0);
        for (int j = t; j < nv4; j += 256) {
            uint4 ra = rp4[j];
            atomicAdd(&cnt[ra.x >> 17], 1);
            atomicAdd(&cnt[ra.y >> 17], 1);
            atomicAdd(&cnt[ra.z >> 17], 1);
            atomicAdd(&cnt[ra.w >> 17], 1);
        }
        for (int i = s0 + (nv4 << 2) + t; i < s1; i += 256)
            atomicAdd(&cnt[recs[i] >> 17], 1);
        __syncthreads();
        int rbase = b << RBS;
        for (int r = t; r < RB; r += 256) {
            int row = rbase + r;
            if (row < n) y4f[4 * (size_t)row + 3] = rsqrtf((float)(cnt[r] + 1));
        }
        // wave0: exclusive scan of 128 row counts -> absolute offsets in rs
        if (t < 64) {
            int cA = cnt[2 * t], cB = cnt[2 * t + 1];
            int s = cA + cB;
            int incl = s;
#pragma unroll
            for (int off = 1; off < 64; off <<= 1) {
                int tt = __shfl_up(incl, off);
                if (t >= off) incl += tt;
            }
            int ex = s0 + incl - s;
            int* rsb = rs + (size_t)b * (RB + 1);
            rsb[2 * t] = ex;
            rsb[2 * t + 1] = ex + cA;
            if (t == 63) rsb[RB] = ex + s;    // == s0 + cntb
        }
    } else {
        int gb = gridDim.x - NBv;
        gemm_rows(x, W, y4f, row3, n, (blockIdx.x - NBv) * 4 + (threadIdx.x >> 6), gb * 4);
    }
}

// K5: one block per bucket. Single-chunk fast path (bucket <= LDSCAP, ~always):
// offsets from rs (no histogram/scan) -> uint4 record loads -> rescatter into
// LDS lrec -> row-order register agg (8-lane group per row). Chunked fallback.
__global__ __launch_bounds__(256) void k_aggrow(const unsigned* __restrict__ recs,
                                                const int* __restrict__ bstart, const int* __restrict__ bcount,
                                                const int* __restrict__ rs,
                                                const float4* __restrict__ y4, const float* __restrict__ bg,
                                                const float* __restrict__ Wo, const float* __restrict__ bo,
                                                float* __restrict__ outH, float* __restrict__ outZ, int n) {
    __shared__ int cnt[RB];
    __shared__ int cur[RB];
    __shared__ int rsl[RB + 1];
    __shared__ int lrec[LDSCAP];
    int b = blockIdx.x, t = threadIdx.x;
    int grp = t >> 3, sub = t & 7;         // 32 groups x 8 lanes
    int s0 = bstart[b], cntb = bcount[b];
    float acc[4][3] = {{0.f, 0.f, 0.f}, {0.f, 0.f, 0.f}, {0.f, 0.f, 0.f}, {0.f, 0.f, 0.f}};
    if (cntb <= LDSCAP) {
        const int* rsb = rs + (size_t)b * (RB + 1);
        for (int i = t; i <= RB; i += 256) {
            int v = rsb[i] - s0;
            rsl[i] = v;
            if (i < RB) cur[i] = v;
        }
        __syncthreads();
        int nv4 = cntb >> 2;
        const uint4* rp4 = (const uint4*)(recs + s0);
        for (int j = t; j < nv4; j += 256) {
            uint4 ra = rp4[j];
            int p0 = atomicAdd(&cur[ra.x >> 17], 1);
            lrec[p0] = (int)(ra.x & 0x1FFFF);
            int p1 = atomicAdd(&cur[ra.y >> 17], 1);
            lrec[p1] = (int)(ra.y & 0x1FFFF);
            int p2 = atomicAdd(&cur[ra.z >> 17], 1);
            lrec[p2] = (int)(ra.z & 0x1FFFF);
            int p3 = atomicAdd(&cur[ra.w >> 17], 1);
            lrec[p3] = (int)(ra.w & 0x1FFFF);
        }
        for (int i = s0 + (nv4 << 2) + t; i < s0 + cntb; i += 256) {
            unsigned rec = recs[i];
            int pos = atomicAdd(&cur[rec >> 17], 1);
            lrec[pos] = (int)(rec & 0x1FFFF);
        }
        __syncthreads();
#pragma unroll
        for (int k = 0; k < 4; ++k) {
            int rr = grp + k * 32;
            int e0 = rsl[rr], e1 = rsl[rr + 1];
            for (int i = e0 + sub; i < e1; i += 8) {
                float4 v = y4[lrec[i]];
                acc[k][0] += v.w * v.x;
                acc[k][1] += v.w * v.y;
                acc[k][2] += v.w * v.z;
            }
        }
    } else {
        for (int c0 = s0; c0 < s0 + cntb; c0 += LDSCAP) {
            int c1 = min(s0 + cntb, c0 + LDSCAP);
            for (int i = t; i < RB; i += 256) cnt[i] = 0;
            __syncthreads();
            for (int i = c0 + t; i < c1; i += 256)
                atomicAdd(&cnt[recs[i] >> 17], 1);
            __syncthreads();
            if (t < 64) {
                int cA = cnt[2 * t], cB = cnt[2 * t + 1];
                int s = cA + cB;
                int incl = s;
#pragma unroll
                for (int off = 1; off < 64; off <<= 1) {
                    int tt = __shfl_up(incl, off);
                    if (t >= off) incl += tt;
                }
                int ex = incl - s;
                rsl[2 * t] = ex;
                rsl[2 * t + 1] = ex + cA;
                cur[2 * t] = ex;
                cur[2 * t + 1] = ex + cA;
                if (t == 63) rsl[RB] = ex + s;
            }
            __syncthreads();
            for (int i = c0 + t; i < c1; i += 256) {
                unsigned rec = recs[i];
                int pos = atomicAdd(&cur[rec >> 17], 1);
                lrec[pos] = (int)(rec & 0x1FFFF);
            }
            __syncthreads();
#pragma unroll
            for (int k = 0; k < 4; ++k) {
                int rr = grp + k * 32;
                int e0 = rsl[rr], e1 = rsl[rr + 1];
                for (int i = e0 + sub; i < e1; i += 8) {
                    float4 v = y4[lrec[i]];
                    acc[k][0] += v.w * v.x;
                    acc[k][1] += v.w * v.y;
                    acc[k][2] += v.w * v.z;
                }
            }
            __syncthreads();
        }
    }
    float b0 = bg[0], b1 = bg[1], b2 = bg[2];
    int rbase = b << RBS;
#pragma unroll
    for (int k = 0; k < 4; ++k) {
        float a0 = acc[k][0], a1 = acc[k][1], a2 = acc[k][2];
#pragma unroll
        for (int o = 4; o; o >>= 1) {
            a0 += __shfl_xor(a0, o);
            a1 += __shfl_xor(a1, o);
            a2 += __shfl_xor(a2, o);
        }
        if (sub == 0) {
            int row = rbase + grp + k * 32;
            if (row < n) {
                float4 yv = y4[row];
                float di = yv.w;
                float h0 = fmaxf(di * (a0 + di * yv.x) + b0, 0.f);
                float h1 = fmaxf(di * (a1 + di * yv.y) + b1, 0.f);
                float h2 = fmaxf(di * (a2 + di * yv.z) + b2, 0.f);
                outH[row * 3 + 0] = h0; outH[row * 3 + 1] = h1; outH[row * 3 + 2] = h2;
#pragma unroll
                for (int c = 0; c < NC; ++c)
                    outZ[row * NC + c] = h0 * Wo[c] + h1 * Wo[NC + c] + h2 * Wo[2 * NC + c] + bo[c];
            }
        }
    }
}

// ---------- atomic fallback (round-1 structure) ----------

__global__ void k_detect_fb(const int* ei, int* flag, int E) {
    __shared__ int anynz;
    if (threadIdx.x == 0) anynz = 0;
    __syncthreads();
    int lim = E < 2048 ? E : 2048;
    int nz = 0;
    for (int i = threadIdx.x; i < lim; i += blockDim.x) nz |= ei[2 * i + 1];
    if (nz) atomicOr(&anynz, 1);
    __syncthreads();
    if (threadIdx.x == 0) *flag = anynz;
}
__global__ void k_init_fb(float* deg, int n) {
    int i = blockIdx.x * blockDim.x + threadIdx.x;
    if (i < n) deg[i] = 1.0f;
}
__global__ void k_degc_fb(const void* ei, const int* flag, float* deg, int E, int n) {
    int i = blockIdx.x * blockDim.x + threadIdx.x;
    if (i >= E) return;
    int d = load_idx(ei, (long long)E + i, *flag);
    if ((unsigned)d < (unsigned)n) atomicAdd(&deg[d], 1.0f);
}
__global__ __launch_bounds__(256) void k_gemm_fb(const float* x, const float* W, float* degdis,
                                                 float* xw, float* agg, int n) {
    __shared__ float wl[NF * NH];
    for (int j = threadIdx.x; j < NF * NH; j += 256) wl[j] = W[j];
    __syncthreads();
    int row = blockIdx.x * 4 + (threadIdx.x >> 6);
    if (row >= n) return;
    int lane = threadIdx.x & 63;
    const float4* xp = (const float4*)(x + (size_t)row * NF + lane * 8);
    float4 a = xp[0], b = xp[1];
    float xv[8] = {a.x, a.y, a.z, a.w, b.x, b.y, b.z, b.w};
    float s0 = 0.f, s1 = 0.f, s2 = 0.f;
    int f0 = lane * 8;
#pragma unroll
    for (int j = 0; j < 8; ++j) {
        float v = xv[j];
        const float* wp = &wl[(f0 + j) * NH];
        s0 += v * wp[0]; s1 += v * wp[1]; s2 += v * wp[2];
    }
#pragma unroll
    for (int off = 32; off; off >>= 1) {
        s0 += __shfl_down(s0, off); s1 += __shfl_down(s1, off); s2 += __shfl_down(s2, off);
    }
    if (lane == 0) {
        float d = degdis[row];
        float di = d > 0.f ? rsqrtf(d) : 0.f;
        degdis[row] = di;
        xw[row * 3 + 0] = s0; xw[row * 3 + 1] = s1; xw[row * 3 + 2] = s2;
        float n2 = di * di;
        agg[row * 3 + 0] = s0 * n2; agg[row * 3 + 1] = s1 * n2; agg[row * 3 + 2] = s2 * n2;
    }
}
__global__ void k_scat_fb(const void* ei, const int* flag, const float* dis, const float* xw,
                          float* agg, int E, int n) {
    int i = blockIdx.x * blockDim.x + threadIdx.x;
    if (i >= E) return;
    int is32 = *flag;
    int s = load_idx(ei, i, is32);
    int d = load_idx(ei, (long long)E + i, is32);
    if ((unsigned)s >= (unsigned)n || (unsigned)d >= (unsigned)n) return;
    float w = dis[s] * dis[d];
    atomicAdd(&agg[d * 3 + 0], xw[s * 3 + 0] * w);
    atomicAdd(&agg[d * 3 + 1], xw[s * 3 + 1] * w);
    atomicAdd(&agg[d * 3 + 2], xw[s * 3 + 2] * w);
}
__global__ void k_final_fb(const float* agg, const float* bg, const float* Wo, const float* bo,
                           float* outH, float* outZ, int n) {
    int i = blockIdx.x * blockDim.x + threadIdx.x;
    if (i >= n) return;
    float h0 = fmaxf(agg[i * 3 + 0] + bg[0], 0.f);
    float h1 = fmaxf(agg[i * 3 + 1] + bg[1], 0.f);
    float h2 = fmaxf(agg[i * 3 + 2] + bg[2], 0.f);
    outH[i * 3 + 0] = h0; outH[i * 3 + 1] = h1; outH[i * 3 + 2] = h2;
#pragma unroll
    for (int c = 0; c < NC; ++c)
        outZ[i * NC + c] = h0 * Wo[c] + h1 * Wo[NC + c] + h2 * Wo[2 * NC + c] + bo[c];
}

// ---------- launch ----------

extern "C" void kernel_launch(void* const* d_in, const int* in_sizes, int n_in,
                              void* d_out, int out_size, void* d_ws, size_t ws_size,
                              hipStream_t stream) {
    const float* x  = (const float*)d_in[0];
    const void*  ei = d_in[1];
    const float* Wg = (const float*)d_in[2];
    const float* bg = (const float*)d_in[3];
    const float* Wo = (const float*)d_in[4];
    const float* bo = (const float*)d_in[5];

    const int N = in_sizes[0] / NF;
    const int E = in_sizes[1] / 2;
    const int NBv = (N + RB - 1) >> RBS;

    float* outH = (float*)d_out;
    float* outZ = outH + (size_t)3 * N;

    int*   wsI = (int*)d_ws;
    float* wsF = (float*)d_ws;

    size_t off = 64;
    int* hist   = wsI + off; off += (size_t)NBMAX * G1;
    int* bstart = wsI + off; off += NBMAX;
    int* bcount = wsI + off; off += NBMAX;
    int* rs     = wsI + off; off += (size_t)NBMAX * (RB + 1);
    off = (off + 3) & ~(size_t)3;
    float* y4   = wsF + off; off += (size_t)4 * N;
    unsigned* recs = (unsigned*)(wsI + off); off += (size_t)E + 4 * NBMAX;  // ceil4 pads

    bool fast = (off * 4 <= ws_size) && (N <= 131072) && (NBv <= NBMAX);

    if (fast) {
        // gemm row fractions co-scheduled with each CSR phase (R19 values)
        int r1 = (int)((long long)N * 30 / 100);
        int r2 = (int)((long long)N * 36 / 100);
        int r3 = (int)((long long)N * 80 / 100);
        k_histgemm<<<G1 + 512, dim3(256), 0, stream>>>(ei, hist, E, NBv, x, Wg, y4, r1);
        k_scangemm<<<NBv + 128, dim3(256), 0, stream>>>(hist, bcount, NBv, x, Wg, y4, r1, r2);
        k_sortgemm<<<G1 + 896, dim3(256), 0, stream>>>(ei, hist, bcount, bstart, recs, E, NBv,
                                                       x, Wg, y4, r2, r3);
        k_deggemm<<<NBv + 512, dim3(256), 0, stream>>>(recs, bstart, bcount, y4, rs,
                                                       N, NBv, x, Wg, r3);
        k_aggrow<<<NBv, dim3(256), 0, stream>>>(recs, bstart, bcount, rs, (const float4*)y4,
                                                bg, Wo, bo, outH, outZ, N);
    } else {
        int* flag  = wsI;
        float* deg = wsF + 64;
        float* xw  = deg + N;
        float* agg = xw + (size_t)3 * N;
        int gN = (N + 255) / 256, gE = (E + 255) / 256;
        dim3 blk(256);
        k_detect_fb<<<1, blk, 0, stream>>>((const int*)ei, flag, E);
        k_init_fb<<<gN, blk, 0, stream>>>(deg, N);
        k_degc_fb<<<gE, blk, 0, stream>>>(ei, flag, deg, E, N);
        k_gemm_fb<<<(N + 3) / 4, blk, 0, stream>>>(x, Wg, deg, xw, agg, N);
        k_scat_fb<<<gE, blk, 0, stream>>>(ei, flag, deg, xw, agg, E, N);
        k_final_fb<<<gN, blk, 0, stream>>>(agg, bg, Wo, bo, outH, outZ, N);
    }
}